// Round 9
// baseline (57.282 us; speedup 1.0000x reference)
//
#include <hip/hip_runtime.h>
#include <math.h>

#define KK 5
#define WPOUT 28
#define PPI 784          // patches per image (28*28)
#define NCH 64
#define NPATCH 25088     // 32*784
#define NPAIR 12544      // patch pairs (A=2*pi, B=2*pi+1 always same row: 28 is even)
#define THREADS 128
#define NNODE 21

typedef _Float16 h2  __attribute__((ext_vector_type(2)));
typedef _Float16 h8  __attribute__((ext_vector_type(8)));
typedef unsigned int u32x32 __attribute__((ext_vector_type(32)));
typedef unsigned int u32x16 __attribute__((ext_vector_type(16)));

__device__ __forceinline__ unsigned pack2(float a, float b) {
    return __builtin_bit_cast(unsigned, __builtin_amdgcn_cvt_pkrtz(a, b));
}
__device__ __forceinline__ h2 uph(unsigned g) { return __builtin_bit_cast(h2, g); }

// One 4-input LUT node for a packed patch pair.
// e8/d8: the node's sigmoided LUT row (e = sigmoid(lut[2k]), d = sigmoid(lut[2k+1]) - e).
// s0 = most significant address bit (contracted last), s3 least significant.
// All arithmetic <2 x half> -> v_pk_fma_f16 / v_pk_add_f16; splats become op_sel.
__device__ __forceinline__ h2 node_pk(h8 e8, h8 d8, h2 s0, h2 s1, h2 s2, h2 s3)
{
    h2 v[8];
#pragma unroll
    for (int k = 0; k < 8; ++k) {
        const h2 es = { e8[k], e8[k] };
        const h2 ds = { d8[k], d8[k] };
        v[k] = s3 * ds + es;
    }
    h2 w[4];
#pragma unroll
    for (int k = 0; k < 4; ++k)
        w[k] = s2 * (v[2 * k + 1] - v[2 * k]) + v[2 * k];
    const h2 u0 = s1 * (w[1] - w[0]) + w[0];
    const h2 u1 = s1 * (w[3] - w[2]) + w[2];
    return s0 * (u1 - u0) + u0;
}

__global__ __launch_bounds__(THREADS)
void dwn_conv_lut_kernel(const float* __restrict__ x,     // [32,1,32,32]
                         const float* __restrict__ lut0,  // [64,16,16]
                         const float* __restrict__ lut1,  // [64,4,16]
                         const float* __restrict__ lut2,  // [64,1,16]
                         const int*   __restrict__ idx0,  // [64,16,4]
                         const int*   __restrict__ idx1,  // [64,4,4]
                         const int*   __restrict__ idx2,  // [64,1,4]
                         float*       __restrict__ out)   // [32,64,28,28]
{
    __shared__ __align__(16) _Float16 lut[NNODE][16];   // [0..7]=e, [8..15]=d, f16

    const int tid = threadIdx.x;
    const int c   = blockIdx.y;

    // ---- stage sigmoided LUTs as f16 (e,d): 21 nodes * 8 pairs = 168 ----
    for (int t = tid; t < NNODE * 8; t += THREADS) {
        const int k = t & 7, node = t >> 3;
        const float* src;
        if (node < 16)      src = lut0 + (c * 16 + node) * 16;
        else if (node < 20) src = lut1 + (c * 4 + (node - 16)) * 16;
        else                src = lut2 + c * 16;
        const float a = src[2 * k], b = src[2 * k + 1];
        const float ea = 1.0f / (1.0f + __expf(-a));
        const float eb = 1.0f / (1.0f + __expf(-b));
        lut[node][k]     = (_Float16)ea;
        lut[node][k + 8] = (_Float16)(eb - ea);
    }

    // ---- two packed pairs per thread: AB and CD (4 patches) ----
    const int piAB = blockIdx.x * (2 * THREADS) + tid;   // 49 * 256 == 12544, no tail
    const int piCD = piAB + THREADS;

    int bQ[2], qQ[2];
    u32x32 pvAB, pvCD;
#pragma unroll
    for (int pp = 0; pp < 2; ++pp) {
        const int p = 2 * (pp == 0 ? piAB : piCD);       // patch A of the pair
        const int b = p / PPI;
        const int q = p - b * PPI;
        const int i = q / WPOUT;
        const int j = q - i * WPOUT;                     // even -> 8B aligned, pair never wraps
        bQ[pp] = b; qQ[pp] = q;
        const float* rp0 = x + b * 1024 + i * 32 + j;
#pragma unroll
        for (int di = 0; di < KK; ++di) {
            const float2* r2 = (const float2*)(rp0 + di * 32);
            const float2 w01 = r2[0], w23 = r2[1], w45 = r2[2];
            const float w[6] = { w01.x, w01.y, w23.x, w23.y, w45.x, w45.y };
#pragma unroll
            for (int dj = 0; dj < KK; ++dj) {
                const unsigned g = pack2(w[dj], w[dj + 1]);   // (patch j.., patch j+1..)
                if (pp == 0) pvAB[di * 5 + dj] = g;
                else         pvCD[di * 5 + dj] = g;
            }
        }
    }

    __syncthreads();   // LUTs ready

    // ---- layer 0: 16 nodes ----
    const int* id0 = idx0 + c * 64;        // block-uniform -> scalar loads
    u32x16 hAB, hCD;
#pragma unroll
    for (int m = 0; m < 16; ++m) {
        const h8* row = (const h8*)&lut[m][0];
        const h8 e8 = row[0], d8 = row[1];            // 2x ds_read_b128
        const int i0 = __builtin_amdgcn_readfirstlane(id0[m * 4 + 0]);
        const int i1 = __builtin_amdgcn_readfirstlane(id0[m * 4 + 1]);
        const int i2 = __builtin_amdgcn_readfirstlane(id0[m * 4 + 2]);
        const int i3 = __builtin_amdgcn_readfirstlane(id0[m * 4 + 3]);
        const h2 a0 = uph(pvAB[i0]), a1 = uph(pvAB[i1]), a2 = uph(pvAB[i2]), a3 = uph(pvAB[i3]);
        const h2 c0 = uph(pvCD[i0]), c1 = uph(pvCD[i1]), c2 = uph(pvCD[i2]), c3 = uph(pvCD[i3]);
        hAB[m] = __builtin_bit_cast(unsigned, node_pk(e8, d8, a0, a1, a2, a3));
        hCD[m] = __builtin_bit_cast(unsigned, node_pk(e8, d8, c0, c1, c2, c3));
    }

    // ---- layer 1: 4 nodes ----
    const int* id1 = idx1 + c * 16;
    unsigned h1ab[4], h1cd[4];             // static-indexed only
#pragma unroll
    for (int m = 0; m < 4; ++m) {
        const h8* row = (const h8*)&lut[16 + m][0];
        const h8 e8 = row[0], d8 = row[1];
        const int i0 = __builtin_amdgcn_readfirstlane(id1[m * 4 + 0]);
        const int i1 = __builtin_amdgcn_readfirstlane(id1[m * 4 + 1]);
        const int i2 = __builtin_amdgcn_readfirstlane(id1[m * 4 + 2]);
        const int i3 = __builtin_amdgcn_readfirstlane(id1[m * 4 + 3]);
        const h2 a0 = uph(hAB[i0]), a1 = uph(hAB[i1]), a2 = uph(hAB[i2]), a3 = uph(hAB[i3]);
        const h2 c0 = uph(hCD[i0]), c1 = uph(hCD[i1]), c2 = uph(hCD[i2]), c3 = uph(hCD[i3]);
        h1ab[m] = __builtin_bit_cast(unsigned, node_pk(e8, d8, a0, a1, a2, a3));
        h1cd[m] = __builtin_bit_cast(unsigned, node_pk(e8, d8, c0, c1, c2, c3));
    }

    // ---- layer 2: 1 node; 4-way uniform select (constant indices after unroll) ----
    const int* id2 = idx2 + c * 4;
    h2 sa[4], sc[4];
#pragma unroll
    for (int jj = 0; jj < 4; ++jj) {
        const int ii = __builtin_amdgcn_readfirstlane(id2[jj]);
        const unsigned ga = (ii == 0) ? h1ab[0] : (ii == 1) ? h1ab[1] : (ii == 2) ? h1ab[2] : h1ab[3];
        const unsigned gc = (ii == 0) ? h1cd[0] : (ii == 1) ? h1cd[1] : (ii == 2) ? h1cd[2] : h1cd[3];
        sa[jj] = uph(ga);
        sc[jj] = uph(gc);
    }
    const h8* row2 = (const h8*)&lut[20][0];
    const h8 e8 = row2[0], d8 = row2[1];
    const h2 rAB = node_pk(e8, d8, sa[0], sa[1], sa[2], sa[3]);
    const h2 rCD = node_pk(e8, d8, sc[0], sc[1], sc[2], sc[3]);

    // ---- store: each pair is two consecutive q (q even) -> aligned float2 ----
    float2* oAB = (float2*)(out + (bQ[0] * NCH + c) * PPI + qQ[0]);
    float2* oCD = (float2*)(out + (bQ[1] * NCH + c) * PPI + qQ[1]);
    *oAB = make_float2((float)rAB[0], (float)rAB[1]);
    *oCD = make_float2((float)rCD[0], (float)rCD[1]);
}

extern "C" void kernel_launch(void* const* d_in, const int* in_sizes, int n_in,
                              void* d_out, int out_size, void* d_ws, size_t ws_size,
                              hipStream_t stream) {
    const float* x    = (const float*)d_in[0];
    const float* lut0 = (const float*)d_in[1];
    const float* lut1 = (const float*)d_in[2];
    const float* lut2 = (const float*)d_in[3];
    const int*   idx0 = (const int*)d_in[4];
    const int*   idx1 = (const int*)d_in[5];
    const int*   idx2 = (const int*)d_in[6];
    float* out = (float*)d_out;

    dim3 grid(NPAIR / (2 * THREADS), NCH);   // 49 x 64
    dim3 block(THREADS);
    dwn_conv_lut_kernel<<<grid, block, 0, stream>>>(x, lut0, lut1, lut2,
                                                    idx0, idx1, idx2, out);
}

// Round 12
// 22.474 us; speedup vs baseline: 2.5488x; 2.5488x over previous
//
#include <hip/hip_runtime.h>
#include <math.h>

#define KK 5
#define WPOUT 28
#define PPI 784          // patches per image (28*28)
#define NCH 64
#define NPATCH 25088     // 32*784
#define NPAIR 12544      // patch pairs (A=2k, B=2k+1 always in same row: 28 even)
#define THREADS 256
#define NNODE 21

typedef float f32x32 __attribute__((ext_vector_type(32)));
typedef float f32x16 __attribute__((ext_vector_type(16)));
typedef _Float16 h2  __attribute__((ext_vector_type(2)));

static __device__ __forceinline__ h2 u2h(unsigned u) { return __builtin_bit_cast(h2, u); }
static __device__ __forceinline__ unsigned h2u(h2 h) { return __builtin_bit_cast(unsigned, h); }
static __device__ __forceinline__ unsigned f2u(float f) { return __builtin_bit_cast(unsigned, f); }
static __device__ __forceinline__ float u2f(unsigned u) { return __builtin_bit_cast(float, u); }

// pack two f32 -> packed f16 pair in one dword (v_cvt_pkrtz_f16_f32)
static __device__ __forceinline__ unsigned packpair(float a, float b) {
    const auto pk = __builtin_amdgcn_cvt_pkrtz(a, b);   // __fp16 ext_vector(2)
    return __builtin_bit_cast(unsigned, pk);
}

// r = s * splat(d.half[ODD]) + splat(e.half[ODD])   (packed f16, both output halves)
// VOP3P op_sel[i] = which half of src i feeds the LOW result half; op_sel_hi[i] the HIGH.
// Splat = same half for both. src0 (s) stays default (lo->lo, hi->hi).
template <int ODD>
static __device__ __forceinline__ unsigned pkfma_splat(unsigned s, unsigned d, unsigned e) {
    unsigned r;
    if constexpr (ODD)
        asm("v_pk_fma_f16 %0, %1, %2, %3 op_sel:[0,1,1] op_sel_hi:[1,1,1]"
            : "=v"(r) : "v"(s), "v"(d), "v"(e));
    else
        asm("v_pk_fma_f16 %0, %1, %2, %3 op_sel:[0,0,0] op_sel_hi:[1,0,0]"
            : "=v"(r) : "v"(s), "v"(d), "v"(e));
    return r;
}

// One 4-input LUT node for a packed patch pair (both patches in each h2).
// E = e[0..7] (f16, 4 dwords), D = d[0..7]; e = sigmoid(lut[2k]), d = sigmoid(lut[2k+1]) - e.
// s0 = most significant address bit (contracted last), s3 least significant.
static __device__ __forceinline__ unsigned node_pair(uint4 E, uint4 D,
                                                     unsigned s0, unsigned s1,
                                                     unsigned s2, unsigned s3) {
    const unsigned Ea[4] = { E.x, E.y, E.z, E.w };
    const unsigned Da[4] = { D.x, D.y, D.z, D.w };
    unsigned v[8];
#pragma unroll
    for (int k = 0; k < 8; k += 2) {
        v[k]     = pkfma_splat<0>(s3, Da[k >> 1], Ea[k >> 1]);
        v[k + 1] = pkfma_splat<1>(s3, Da[k >> 1], Ea[k >> 1]);
    }
    const h2 s2h = u2h(s2), s1h = u2h(s1), s0h = u2h(s0);
    h2 w[4];
#pragma unroll
    for (int k = 0; k < 4; ++k) {
        const h2 ve = u2h(v[2 * k]), vo = u2h(v[2 * k + 1]);
        w[k] = s2h * (vo - ve) + ve;        // full-register v_pk ops, no splats
    }
    const h2 u0 = s1h * (w[1] - w[0]) + w[0];
    const h2 u1 = s1h * (w[3] - w[2]) + w[2];
    return h2u(s0h * (u1 - u0) + u0);
}

__global__ __launch_bounds__(THREADS)
void dwn_conv_lut_kernel(const float* __restrict__ x,     // [32,1,32,32]
                         const float* __restrict__ lut0,  // [64,16,16]
                         const float* __restrict__ lut1,  // [64,4,16]
                         const float* __restrict__ lut2,  // [64,1,16]
                         const int*   __restrict__ idx0,  // [64,16,4]
                         const int*   __restrict__ idx1,  // [64,4,4]
                         const int*   __restrict__ idx2,  // [64,1,4]
                         float*       __restrict__ out)   // [32,64,28,28]
{
    __shared__ __align__(16) _Float16 lut[NNODE][16];   // [0..7]=e, [8..15]=d (f16), 32B/row

    const int tid = threadIdx.x;
    const int c   = blockIdx.y;

    // ---- stage sigmoided LUTs as f16 (e,d): 21 nodes * 8 pairs = 168 ----
    if (tid < NNODE * 8) {
        const int k = tid & 7, node = tid >> 3;
        const float* src;
        if (node < 16)      src = lut0 + (c * 16 + node) * 16;
        else if (node < 20) src = lut1 + (c * 4 + (node - 16)) * 16;
        else                src = lut2 + c * 16;
        const float a = src[2 * k], b = src[2 * k + 1];
        const float ea = 1.0f / (1.0f + __expf(-a));
        const float eb = 1.0f / (1.0f + __expf(-b));
        lut[node][k]     = (_Float16)ea;
        lut[node][k + 8] = (_Float16)(eb - ea);
    }

    // ---- one packed patch pair per thread (A=2*pi, B=2*pi+1, same row) ----
    const int pi = blockIdx.x * THREADS + tid;   // 49*256 == 12544, no tail
    const int p  = 2 * pi;                       // patch A
    const int b  = p / PPI;
    const int q  = p - b * PPI;                  // even
    const int i  = q / WPOUT;
    const int j  = q - i * WPOUT;                // even -> 8B aligned; j<=26 so pair in-row

    const float* rp0 = x + b * 1024 + i * 32 + j;
    f32x32 pv;                                   // f32-typed (proven movrel); contents = h2 pairs
#pragma unroll
    for (int di = 0; di < KK; ++di) {
        const float2* r2 = (const float2*)(rp0 + di * 32);
        const float2 w01 = r2[0], w23 = r2[1], w45 = r2[2];
        const float w[6] = { w01.x, w01.y, w23.x, w23.y, w45.x, w45.y };
#pragma unroll
        for (int dj = 0; dj < KK; ++dj) {
            // (patch A value, patch B value) for kernel offset (di,dj)
            pv[di * 5 + dj] = u2f(packpair(w[dj], w[dj + 1]));
        }
    }

    __syncthreads();   // LUTs ready

    // ---- layer 0: 16 nodes; uniform-index movrel gathers ----
    const int* id0 = idx0 + c * 64;   // block-uniform -> scalar loads
    f32x16 h0;
#pragma unroll
    for (int m = 0; m < 16; ++m) {
        const uint4* row = (const uint4*)&lut[m][0];
        const uint4 E = row[0], D = row[1];          // 2x ds_read_b128
        const int i0 = __builtin_amdgcn_readfirstlane(id0[m * 4 + 0]);
        const int i1 = __builtin_amdgcn_readfirstlane(id0[m * 4 + 1]);
        const int i2 = __builtin_amdgcn_readfirstlane(id0[m * 4 + 2]);
        const int i3 = __builtin_amdgcn_readfirstlane(id0[m * 4 + 3]);
        const unsigned r = node_pair(E, D, f2u(pv[i0]), f2u(pv[i1]), f2u(pv[i2]), f2u(pv[i3]));
        h0[m] = u2f(r);
    }

    // ---- layer 1: 4 nodes; movrel gathers from h0 ----
    const int* id1 = idx1 + c * 16;
    unsigned h1[4];                   // static-indexed only
#pragma unroll
    for (int m = 0; m < 4; ++m) {
        const uint4* row = (const uint4*)&lut[16 + m][0];
        const uint4 E = row[0], D = row[1];
        const int i0 = __builtin_amdgcn_readfirstlane(id1[m * 4 + 0]);
        const int i1 = __builtin_amdgcn_readfirstlane(id1[m * 4 + 1]);
        const int i2 = __builtin_amdgcn_readfirstlane(id1[m * 4 + 2]);
        const int i3 = __builtin_amdgcn_readfirstlane(id1[m * 4 + 3]);
        h1[m] = node_pair(E, D, f2u(h0[i0]), f2u(h0[i1]), f2u(h0[i2]), f2u(h0[i3]));
    }

    // ---- layer 2: 1 node; 4-way uniform select (constant after unroll) ----
    const int* id2 = idx2 + c * 4;
    unsigned s[4];
#pragma unroll
    for (int jj = 0; jj < 4; ++jj) {
        const int ii = __builtin_amdgcn_readfirstlane(id2[jj]);
        s[jj] = (ii == 0) ? h1[0] : (ii == 1) ? h1[1] : (ii == 2) ? h1[2] : h1[3];
    }
    const uint4* row2 = (const uint4*)&lut[20][0];
    const h2 r = u2h(node_pair(row2[0], row2[1], s[0], s[1], s[2], s[3]));

    // ---- store: two consecutive q (q even) -> aligned float2 ----
    float2* o = (float2*)(out + (b * NCH + c) * PPI + q);
    *o = make_float2((float)r[0], (float)r[1]);
}

extern "C" void kernel_launch(void* const* d_in, const int* in_sizes, int n_in,
                              void* d_out, int out_size, void* d_ws, size_t ws_size,
                              hipStream_t stream) {
    const float* x    = (const float*)d_in[0];
    const float* lut0 = (const float*)d_in[1];
    const float* lut1 = (const float*)d_in[2];
    const float* lut2 = (const float*)d_in[3];
    const int*   idx0 = (const int*)d_in[4];
    const int*   idx1 = (const int*)d_in[5];
    const int*   idx2 = (const int*)d_in[6];
    float* out = (float*)d_out;

    dim3 grid(NPAIR / THREADS, NCH);   // 49 x 64
    dim3 block(THREADS);
    dwn_conv_lut_kernel<<<grid, block, 0, stream>>>(x, lut0, lut1, lut2,
                                                    idx0, idx1, idx2, out);
}